// Round 6
// baseline (113.467 us; speedup 1.0000x reference)
//
#include <hip/hip_runtime.h>

typedef __attribute__((ext_vector_type(4))) float f4;
typedef __attribute__((ext_vector_type(4))) float f32x4;
typedef __attribute__((ext_vector_type(8))) __bf16 bf8;
typedef __attribute__((ext_vector_type(8))) unsigned short us8;

#define NB 64
#define LSEQ 40
#define D_DIM 768
#define NPATCH 576
#define SEQ 617
#define K_DIM 768
#define M_DIM (NB * NPATCH)   // 36864
#define A_BYTES 56623104      // M_DIM * K_DIM * 2
#define GEMM_LDS 131072

static __device__ __forceinline__ unsigned short f2bf(float f) {
    union { float f; unsigned u; } v; v.f = f;
    unsigned r = v.u + 0x7FFFu + ((v.u >> 16) & 1u);
    return (unsigned short)(r >> 16);
}

static __device__ __forceinline__ void gload_lds16(const void* g, void* l) {
    __builtin_amdgcn_global_load_lds(
        (const __attribute__((address_space(1))) unsigned int*)g,
        (__attribute__((address_space(3))) unsigned int*)l,
        16, 0, 0);
}

#define MFMA16(a, b, c) __builtin_amdgcn_mfma_f32_16x16x32_bf16((a), (b), (c), 0, 0, 0)

// ---- convert conv_w (768x768 f32) -> bf16, stored chunk-swizzled ----
__global__ __launch_bounds__(256) void convert_w(const float* __restrict__ w,
                                                 unsigned short* __restrict__ o) {
    int t = blockIdx.x * 256 + threadIdx.x;   // 73728 threads (768*96 chunks)
    int cs = t % 96, n = t / 96;
    int blk = cs >> 3, c = cs & 7;
    int cl = (blk << 3) | (c ^ (n & 7));      // logical chunk
    const float* s = w + (size_t)n * 768 + cl * 8;
    f4 a = *(const f4*)s;
    f4 b = *(const f4*)(s + 4);
    us8 r;
    r[0]=f2bf(a[0]); r[1]=f2bf(a[1]); r[2]=f2bf(a[2]); r[3]=f2bf(a[3]);
    r[4]=f2bf(b[0]); r[5]=f2bf(b[1]); r[6]=f2bf(b[2]); r[7]=f2bf(b[3]);
    *(us8*)(o + (size_t)n * 768 + cs * 8) = r;
}

// ---- gather pixel patches into bf16 A [M=36864][K=768], chunk-swizzled ----
__global__ __launch_bounds__(256) void convert_patches(const float* __restrict__ px,
                                                       unsigned short* __restrict__ A) {
    int t = blockIdx.x * 256 + threadIdx.x;   // 3538944 threads
    int cs = t % 96, m = t / 96;
    int blk = cs >> 3, c = cs & 7;
    int cl = (blk << 3) | (c ^ (m & 7));      // logical chunk -> k = cl*8
    int k = cl * 8;
    int b = m / 576, p = m % 576;
    int ph = p / 24, pw = p % 24;
    int ch = k >> 8, rr = k & 255, i = rr >> 4, j = rr & 15;  // j in {0,8}
    const float* s = px + ((size_t)(b * 3 + ch) * 384 + ph * 16 + i) * 384 + pw * 16 + j;
    f4 a = *(const f4*)s;
    f4 d = *(const f4*)(s + 4);
    us8 o;
    o[0]=f2bf(a[0]); o[1]=f2bf(a[1]); o[2]=f2bf(a[2]); o[3]=f2bf(a[3]);
    o[4]=f2bf(d[0]); o[5]=f2bf(d[1]); o[6]=f2bf(d[2]); o[7]=f2bf(d[3]);
    *(us8*)(A + (size_t)m * 768 + cs * 8) = o;
}

// ---- text: gather + LayerNorm + mod_type[0], one wave per (b,l) row ----
__global__ __launch_bounds__(256) void text_kernel(
    const int* __restrict__ ids, const int* __restrict__ tti,
    const float* __restrict__ we, const float* __restrict__ pe,
    const float* __restrict__ tke, const float* __restrict__ g,
    const float* __restrict__ bb, const float* __restrict__ mod,
    float* __restrict__ out) {
    int row = blockIdx.x * 4 + (threadIdx.x >> 6);   // 2560 rows
    int lane = threadIdx.x & 63;
    int b = row / 40, l = row % 40;
    const float* wp = we + (size_t)ids[row] * 768;
    const float* pp = pe + l * 768;
    const float* tp = tke + (size_t)tti[row] * 768;
    f4 x[3];
    float s = 0.f, q = 0.f;
#pragma unroll
    for (int j = 0; j < 3; ++j) {
        int d = j * 256 + lane * 4;
        f4 v = *(const f4*)(wp + d);
        f4 v2 = *(const f4*)(pp + d);
        f4 v3 = *(const f4*)(tp + d);
        v = v + v2 + v3;
        x[j] = v;
        s += v[0] + v[1] + v[2] + v[3];
        q += v[0]*v[0] + v[1]*v[1] + v[2]*v[2] + v[3]*v[3];
    }
#pragma unroll
    for (int o = 32; o > 0; o >>= 1) { s += __shfl_xor(s, o); q += __shfl_xor(q, o); }
    float mean = s * (1.0f / 768.0f);
    float var = q * (1.0f / 768.0f) - mean * mean;
    float rstd = rsqrtf(var + 1e-12f);
    float* op = out + ((size_t)b * SEQ + 1 + l) * 768;
#pragma unroll
    for (int j = 0; j < 3; ++j) {
        int d = j * 256 + lane * 4;
        f4 gg = *(const f4*)(g + d);
        f4 bv = *(const f4*)(bb + d);
        f4 mm = *(const f4*)(mod + d);
        f4 r = (x[j] - mean) * rstd * gg + bv + mm;
        *(f4*)(op + d) = r;
    }
}

// ---- patch GEMM: 256x256, BK=64, 8 waves, 8-phase counted-vmcnt pipeline ----
// Fixed-role buffers: Ae/Ao/Be/Bo (tile parity). Per K-tile = 4 phases:
// {ds_read frags || stage half-tiles -> bar -> setprio+16 MFMA -> bar}.
// Stage windows (g = phase 1..8 of the 2-tile iteration):
//   prologue: A(0)->Ae, B(0)->Be, B(1)->Bo  [the missing B(1) was R5's race]
//   g1: A(t1)h0   g2: A(t1)h1 + B(t0+2)h0   g3: B(t0+2)h1
//   g5: A(t0+2)h0 g6: A(t0+2)h1 + B(t1+2)h0 g7: B(t1+2)h1
// vmcnt ledger (12 outstanding at g4/g8 steady state): vmcnt(4) at g4
// drains Bo[i-1]+Ao = g5's reads; vmcnt(4) at g8 drains Be+Ae = next g1's
// reads. i=0: g4 sees 8, drains Ao (Bo prologue-drained). i=5: vmcnt(0)
// at g4 (tail), nothing at g8. Every overwrite is after its last reader's
// post-MFMA barrier.
__global__ __launch_bounds__(512, 2) void gemm_patch(
    const __bf16* __restrict__ A, const __bf16* __restrict__ W,
    const float* __restrict__ conv_b, const float* __restrict__ vis_pos,
    const float* __restrict__ mod, float* __restrict__ out) {
    extern __shared__ __align__(16) char smem[];   // 128 KB
    char* Ae = smem;            // even K-tiles of A (32 KB: 256 rows x 128 B)
    char* Ao = smem + 32768;    // odd  K-tiles of A
    char* Be = smem + 65536;    // even K-tiles of B
    char* Bo = smem + 98304;    // odd  K-tiles of B

    const int tid = threadIdx.x;
    const int w = tid >> 6, lane = tid & 63;

    // bijective XCD remap: 432 blocks = 8 XCDs * 54
    int lid = blockIdx.x;
    int gwi = (lid & 7) * 54 + (lid >> 3);
    const int tile_n = (gwi % 3) * 256;
    const int tile_m = (gwi / 3) * 256;
    const int wm = w >> 2, wn = w & 3;
    const int wr = wm * 128, wc = wn * 64;

    f32x4 acc[8][4] = {};
    const char* Ab = (const char*)A;
    const char* Bb = (const char*)W;
    const int rsel = lane & 15;
    const int hk = lane >> 4;

    auto STAGE_H = [&](const char* gbase, int trow, int kt, char* lbase, int h) {
#pragma unroll
        for (int i = 0; i < 2; ++i) {
            int uoff = (w << 10) + i * 8192;       // wave-uniform, [0,16K)
            int loff = uoff + (lane << 4);
            int row = (loff >> 7) + h * 128;
            int col = loff & 127;
            gload_lds16(gbase + (size_t)(trow + row) * 1536 + kt * 128 + col,
                        lbase + h * 16384 + uoff);
        }
    };
    auto BAR = [&]() {
        __builtin_amdgcn_sched_barrier(0);
        __builtin_amdgcn_s_barrier();
        __builtin_amdgcn_sched_barrier(0);
    };

    bf8 bfr[4][2], afr[2][2];
    auto READ_B = [&](const char* Bl) {
#pragma unroll
        for (int ni = 0; ni < 4; ++ni)
#pragma unroll
            for (int ks = 0; ks < 2; ++ks) {
                int r = wc + ni * 16 + rsel;
                int cst = (ks * 4 + hk) ^ (r & 7);
                bfr[ni][ks] = *(const bf8*)(Bl + r * 128 + cst * 16);
            }
    };

    // prologue: tile 0 A+B, tile 1 B (tile 1 A staged in g1/g2), drain once
    STAGE_H(Ab, tile_m, 0, Ae, 0); STAGE_H(Ab, tile_m, 0, Ae, 1);
    STAGE_H(Bb, tile_n, 0, Be, 0); STAGE_H(Bb, tile_n, 0, Be, 1);
    STAGE_H(Bb, tile_n, 1, Bo, 0); STAGE_H(Bb, tile_n, 1, Bo, 1);
    asm volatile("s_waitcnt vmcnt(0)" ::: "memory");
    BAR();

    for (int i = 0; i < 6; ++i) {
        const int t0 = 2 * i, t1 = 2 * i + 1;
        const bool sE = (t0 + 2 < 12);   // stage even pair-successor?
        const bool sO = (t1 + 2 < 12);   // stage odd successor?

#define PHASE(Abuf, Bbuf, Q, DO_B, STAGES)                                   \
        {                                                                    \
            if (DO_B) READ_B(Bbuf);                                          \
            _Pragma("unroll")                                                \
            for (int j = 0; j < 2; ++j)                                      \
                _Pragma("unroll")                                            \
                for (int ks = 0; ks < 2; ++ks) {                             \
                    int r = wr + (2 * (Q) + j) * 16 + rsel;                  \
                    int cst = (ks * 4 + hk) ^ (r & 7);                       \
                    afr[j][ks] = *(const bf8*)((Abuf) + r * 128 + cst * 16); \
                }                                                            \
            STAGES                                                           \
            BAR();                                                           \
            __builtin_amdgcn_s_setprio(1);                                   \
            _Pragma("unroll")                                                \
            for (int j = 0; j < 2; ++j)                                      \
                _Pragma("unroll")                                            \
                for (int ni = 0; ni < 4; ++ni) {                             \
                    acc[2 * (Q) + j][ni] =                                   \
                        MFMA16(afr[j][0], bfr[ni][0], acc[2 * (Q) + j][ni]); \
                    acc[2 * (Q) + j][ni] =                                   \
                        MFMA16(afr[j][1], bfr[ni][1], acc[2 * (Q) + j][ni]); \
                }                                                            \
            __builtin_amdgcn_s_setprio(0);                                   \
        }

        // ---- group t0 (Ae, Be) ----
        PHASE(Ae, Be, 0, true,  { STAGE_H(Ab, tile_m, t1, Ao, 0); })
        BAR();
        PHASE(Ae, Be, 1, false, { STAGE_H(Ab, tile_m, t1, Ao, 1);
                                  if (sE) STAGE_H(Bb, tile_n, t0 + 2, Be, 0); })
        BAR();
        PHASE(Ae, Be, 2, false, { if (sE) STAGE_H(Bb, tile_n, t0 + 2, Be, 1); })
        BAR();
        PHASE(Ae, Be, 3, false, { })
        if (i < 5) { asm volatile("s_waitcnt vmcnt(4)" ::: "memory"); }
        else       { asm volatile("s_waitcnt vmcnt(0)" ::: "memory"); }
        BAR();

        // ---- group t1 (Ao, Bo) ----
        PHASE(Ao, Bo, 0, true,  { if (sE) STAGE_H(Ab, tile_m, t0 + 2, Ae, 0); })
        BAR();
        PHASE(Ao, Bo, 1, false, { if (sE) STAGE_H(Ab, tile_m, t0 + 2, Ae, 1);
                                  if (sO) STAGE_H(Bb, tile_n, t1 + 2, Bo, 0); })
        BAR();
        PHASE(Ao, Bo, 2, false, { if (sO) STAGE_H(Bb, tile_n, t1 + 2, Bo, 1); })
        BAR();
        PHASE(Ao, Bo, 3, false, { })
        if (i < 5) {
            asm volatile("s_waitcnt vmcnt(4)" ::: "memory");
            BAR();
        }
#undef PHASE
    }

    const int lr = (lane >> 4) * 4;
    const int lc = lane & 15;
#pragma unroll
    for (int mi = 0; mi < 8; ++mi) {
#pragma unroll
        for (int r = 0; r < 4; ++r) {
            int gm = tile_m + wr + mi * 16 + lr + r;
            int bimg = gm / 576, pp = gm % 576;
            size_t orow = (size_t)bimg * SEQ + 1 + LSEQ + pp;
#pragma unroll
            for (int ni = 0; ni < 4; ++ni) {
                int gn = tile_n + wc + ni * 16 + lc;
                float v = acc[mi][ni][r] + conv_b[gn] +
                          vis_pos[(size_t)(pp + 1) * 768 + gn] + mod[768 + gn];
                out[orow * 768 + gn] = v;
            }
        }
    }
}

// ---- CLS rows + masks ----
__global__ __launch_bounds__(256) void cls_masks(const float* __restrict__ cls,
                                                 const int* __restrict__ am,
                                                 float* __restrict__ out) {
    int t = blockIdx.x * 256 + threadIdx.x;
    if (t < NB * 768) {
        int b = t / 768, d = t % 768;
        out[(size_t)b * SEQ * 768 + d] = cls[d];
    } else if (t < NB * 768 + NB * SEQ) {
        int i = t - NB * 768;
        int b = i / SEQ, s = i % SEQ;
        float v = 1.0f;
        if (s >= 1 && s <= LSEQ) v = (float)am[b * LSEQ + s - 1];
        out[(size_t)NB * SEQ * 768 + i] = v;
    }
}

extern "C" void kernel_launch(void* const* d_in, const int* in_sizes, int n_in,
                              void* d_out, int out_size, void* d_ws, size_t ws_size,
                              hipStream_t stream) {
    const int*   ids  = (const int*)d_in[0];
    const int*   am   = (const int*)d_in[1];
    const int*   tti  = (const int*)d_in[2];
    const float* px   = (const float*)d_in[3];
    const float* we   = (const float*)d_in[5];
    const float* pe   = (const float*)d_in[6];
    const float* tke  = (const float*)d_in[7];
    const float* lng  = (const float*)d_in[8];
    const float* lnb  = (const float*)d_in[9];
    const float* cw   = (const float*)d_in[10];
    const float* cb   = (const float*)d_in[11];
    const float* cls  = (const float*)d_in[12];
    const float* vpos = (const float*)d_in[13];
    const float* mod  = (const float*)d_in[14];
    float* out = (float*)d_out;

    __bf16* Abf = (__bf16*)d_ws;
    __bf16* Wbf = (__bf16*)((char*)d_ws + A_BYTES);

    hipFuncSetAttribute((const void*)gemm_patch,
                        hipFuncAttributeMaxDynamicSharedMemorySize, GEMM_LDS);

    convert_w<<<288, 256, 0, stream>>>(cw, (unsigned short*)Wbf);
    convert_patches<<<13824, 256, 0, stream>>>(px, (unsigned short*)Abf);
    text_kernel<<<640, 256, 0, stream>>>(ids, tti, we, pe, tke, lng, lnb, mod, out);
    gemm_patch<<<432, 512, GEMM_LDS, stream>>>(Abf, Wbf, cb, vpos, mod, out);
    cls_masks<<<347, 256, 0, stream>>>(cls, am, out);
}

// Round 7
// 101.518 us; speedup vs baseline: 1.1177x; 1.1177x over previous
//
#include <hip/hip_runtime.h>

typedef __attribute__((ext_vector_type(4))) float f4;
typedef __attribute__((ext_vector_type(4))) float f32x4;
typedef __attribute__((ext_vector_type(8))) __bf16 bf8;
typedef __attribute__((ext_vector_type(8))) unsigned short us8;

#define NB 64
#define LSEQ 40
#define D_DIM 768
#define NPATCH 576
#define SEQ 617
#define K_DIM 768
#define M_DIM (NB * NPATCH)   // 36864
#define GEMM_LDS 131072

static __device__ __forceinline__ unsigned short f2bf(float f) {
    union { float f; unsigned u; } v; v.f = f;
    unsigned r = v.u + 0x7FFFu + ((v.u >> 16) & 1u);
    return (unsigned short)(r >> 16);
}

static __device__ __forceinline__ void gload_lds16(const void* g, void* l) {
    __builtin_amdgcn_global_load_lds(
        (const __attribute__((address_space(1))) unsigned int*)g,
        (__attribute__((address_space(3))) unsigned int*)l,
        16, 0, 0);
}

#define MFMA16(a, b, c) __builtin_amdgcn_mfma_f32_16x16x32_bf16((a), (b), (c), 0, 0, 0)

// ---- convert conv_w (768x768 f32) -> bf16, stored chunk-swizzled ----
// stored[n][blk][c] = logical[n][blk][c ^ (n&7)], 16B chunks, 128B blocks.
__global__ __launch_bounds__(256) void convert_w(const float* __restrict__ w,
                                                 unsigned short* __restrict__ o) {
    int t = blockIdx.x * 256 + threadIdx.x;   // 73728 threads (768*96 chunks)
    int cs = t % 96, n = t / 96;
    int blk = cs >> 3, c = cs & 7;
    int cl = (blk << 3) | (c ^ (n & 7));      // logical chunk
    const float* s = w + (size_t)n * 768 + cl * 8;
    f4 a = *(const f4*)s;
    f4 b = *(const f4*)(s + 4);
    us8 r;
    r[0]=f2bf(a[0]); r[1]=f2bf(a[1]); r[2]=f2bf(a[2]); r[3]=f2bf(a[3]);
    r[4]=f2bf(b[0]); r[5]=f2bf(b[1]); r[6]=f2bf(b[2]); r[7]=f2bf(b[3]);
    *(us8*)(o + (size_t)n * 768 + cs * 8) = r;
}

// ---- text: gather + LayerNorm + mod_type[0], one wave per (b,l) row ----
__global__ __launch_bounds__(256) void text_kernel(
    const int* __restrict__ ids, const int* __restrict__ tti,
    const float* __restrict__ we, const float* __restrict__ pe,
    const float* __restrict__ tke, const float* __restrict__ g,
    const float* __restrict__ bb, const float* __restrict__ mod,
    float* __restrict__ out) {
    int row = blockIdx.x * 4 + (threadIdx.x >> 6);   // 2560 rows
    int lane = threadIdx.x & 63;
    int b = row / 40, l = row % 40;
    const float* wp = we + (size_t)ids[row] * 768;
    const float* pp = pe + l * 768;
    const float* tp = tke + (size_t)tti[row] * 768;
    f4 x[3];
    float s = 0.f, q = 0.f;
#pragma unroll
    for (int j = 0; j < 3; ++j) {
        int d = j * 256 + lane * 4;
        f4 v = *(const f4*)(wp + d);
        f4 v2 = *(const f4*)(pp + d);
        f4 v3 = *(const f4*)(tp + d);
        v = v + v2 + v3;
        x[j] = v;
        s += v[0] + v[1] + v[2] + v[3];
        q += v[0]*v[0] + v[1]*v[1] + v[2]*v[2] + v[3]*v[3];
    }
#pragma unroll
    for (int o = 32; o > 0; o >>= 1) { s += __shfl_xor(s, o); q += __shfl_xor(q, o); }
    float mean = s * (1.0f / 768.0f);
    float var = q * (1.0f / 768.0f) - mean * mean;
    float rstd = rsqrtf(var + 1e-12f);
    float* op = out + ((size_t)b * SEQ + 1 + l) * 768;
#pragma unroll
    for (int j = 0; j < 3; ++j) {
        int d = j * 256 + lane * 4;
        f4 gg = *(const f4*)(g + d);
        f4 bv = *(const f4*)(bb + d);
        f4 mm = *(const f4*)(mod + d);
        f4 r = (x[j] - mean) * rstd * gg + bv + mm;
        *(f4*)(op + d) = r;
    }
}

// ---- fused patch GEMM: 256x256, BK=64, 8 waves, R4 skeleton ----
// A is staged straight from pixel_values: per K-tile, 8x16B f32 loads ->
// regs issued at tile top (in flight across the 64 MFMAs), converted to
// bf16 + swizzled ds_write after the MFMAs, before __syncthreads.
// B staged via global_load_lds from pre-swizzled bf16 W (convert_w).
// K-tile kt -> channel c=kt>>2, pixel rows i=(kt&3)*4..+4.
// Race ledger: Abuf/Bbuf[p^1] last read at tile t-1 (before t's entry
// barrier); A ds_writes drain via __syncthreads' lgkmcnt(0); areg
// consumed (WRITE_A) before next LOAD_A overwrites.
__global__ __launch_bounds__(512, 2) void gemm_patch(
    const float* __restrict__ px, const __bf16* __restrict__ W,
    const float* __restrict__ conv_b, const float* __restrict__ vis_pos,
    const float* __restrict__ mod, float* __restrict__ out) {
    extern __shared__ __align__(16) char smem[];   // 128 KB
    char* Ab0 = smem;            // A buffers: 256 rows x 128 B
    char* Ab1 = smem + 32768;
    char* Bb0 = smem + 65536;    // B buffers
    char* Bb1 = smem + 98304;

    const int tid = threadIdx.x;
    const int w = tid >> 6, lane = tid & 63;

    // bijective XCD remap: 432 blocks = 8 XCDs * 54
    int lid = blockIdx.x;
    int gwi = (lid & 7) * 54 + (lid >> 3);
    const int tile_n = (gwi % 3) * 256;
    const int tile_m = (gwi / 3) * 256;
    const int wm = w >> 2, wn = w & 3;
    const int wr = wm * 128, wc = wn * 64;

    f32x4 acc[8][4] = {};
    const char* Bb = (const char*)W;
    const int rsel = lane & 15;
    const int hk = lane >> 4;

    // ---- A-staging lane geometry (constant across tiles) ----
    const int arow = tid & 255;          // A-tile row this thread stages
    const int ii0 = tid >> 8;            // chunks ii = ii0, ii0+2
    {
        // hoisted; recomputed cheaply below via pxrow
    }
    int agm = tile_m + arow;
    int abimg = agm / 576, ap = agm % 576;
    int aph = ap / 24, apw = ap % 24;
    const float* pxrow = px + (size_t)abimg * 3 * 147456
                            + (size_t)(aph * 16) * 384 + apw * 16;

    f4 areg[2][4];
    auto LOAD_A = [&](int kt) {
        int c = kt >> 2, i0 = (kt & 3) << 2;
#pragma unroll
        for (int rep = 0; rep < 2; ++rep) {
            int i = i0 + ii0 + rep * 2;
            const float* s = pxrow + (size_t)c * 147456 + i * 384;
#pragma unroll
            for (int q = 0; q < 4; ++q) areg[rep][q] = *(const f4*)(s + q * 4);
        }
    };
    auto WRITE_A = [&](char* dst) {
#pragma unroll
        for (int rep = 0; rep < 2; ++rep) {
            int ii = ii0 + rep * 2;
            us8 h0, h1;
#pragma unroll
            for (int q = 0; q < 2; ++q) {
                h0[q*4+0]=f2bf(areg[rep][q][0]); h0[q*4+1]=f2bf(areg[rep][q][1]);
                h0[q*4+2]=f2bf(areg[rep][q][2]); h0[q*4+3]=f2bf(areg[rep][q][3]);
                h1[q*4+0]=f2bf(areg[rep][q+2][0]); h1[q*4+1]=f2bf(areg[rep][q+2][1]);
                h1[q*4+2]=f2bf(areg[rep][q+2][2]); h1[q*4+3]=f2bf(areg[rep][q+2][3]);
            }
            int cc0 = ii * 2;
            *(us8*)(dst + arow * 128 + ((cc0    ) ^ (arow & 7)) * 16) = h0;
            *(us8*)(dst + arow * 128 + ((cc0 + 1) ^ (arow & 7)) * 16) = h1;
        }
    };
    auto STAGE_B = [&](char* lbase, int kt) {
#pragma unroll
        for (int i = 0; i < 4; ++i) {
            int uoff = (w << 10) + i * 8192;       // wave-uniform
            int loff = uoff + (lane << 4);
            int row = loff >> 7, col = loff & 127;
            gload_lds16(Bb + (size_t)(tile_n + row) * 1536 + kt * 128 + col,
                        lbase + uoff);
        }
    };

    // prologue: tile 0
    LOAD_A(0);
    STAGE_B(Bb0, 0);
    WRITE_A(Ab0);            // compiler inserts vmcnt wait for areg
    __syncthreads();         // drains B gload_lds + A ds_writes

    for (int t = 0; t < 12; ++t) {
        char* Ac = (t & 1) ? Ab1 : Ab0;
        char* Bc = (t & 1) ? Bb1 : Bb0;
        char* An = (t & 1) ? Ab0 : Ab1;
        char* Bn = (t & 1) ? Bb0 : Bb1;

        if (t < 11) {
            LOAD_A(t + 1);       // f32 pixel loads -> regs, in flight over MFMAs
            STAGE_B(Bn, t + 1);  // bf16 W -> LDS direct
        }

        bf8 a0[4][2], b0[4][2];
#pragma unroll
        for (int mi = 0; mi < 4; ++mi) {
            int r = wr + mi * 16 + rsel;
#pragma unroll
            for (int ks = 0; ks < 2; ++ks) {
                int cst = (ks * 4 + hk) ^ (r & 7);
                a0[mi][ks] = *(const bf8*)(Ac + r * 128 + cst * 16);
            }
        }
#pragma unroll
        for (int ni = 0; ni < 4; ++ni) {
            int r = wc + ni * 16 + rsel;
#pragma unroll
            for (int ks = 0; ks < 2; ++ks) {
                int cst = (ks * 4 + hk) ^ (r & 7);
                b0[ni][ks] = *(const bf8*)(Bc + r * 128 + cst * 16);
            }
        }
#pragma unroll
        for (int mi = 0; mi < 4; ++mi)
#pragma unroll
            for (int ni = 0; ni < 4; ++ni) {
                acc[mi][ni] = MFMA16(a0[mi][0], b0[ni][0], acc[mi][ni]);
                acc[mi][ni] = MFMA16(a0[mi][1], b0[ni][1], acc[mi][ni]);
            }

        bf8 a1[4][2];
#pragma unroll
        for (int mi = 0; mi < 4; ++mi) {
            int r = wr + 64 + mi * 16 + rsel;
#pragma unroll
            for (int ks = 0; ks < 2; ++ks) {
                int cst = (ks * 4 + hk) ^ (r & 7);
                a1[mi][ks] = *(const bf8*)(Ac + r * 128 + cst * 16);
            }
        }
#pragma unroll
        for (int mi = 0; mi < 4; ++mi)
#pragma unroll
            for (int ni = 0; ni < 4; ++ni) {
                acc[4 + mi][ni] = MFMA16(a1[mi][0], b0[ni][0], acc[4 + mi][ni]);
                acc[4 + mi][ni] = MFMA16(a1[mi][1], b0[ni][1], acc[4 + mi][ni]);
            }

        if (t < 11) {
            WRITE_A(An);         // cvt + swizzled ds_write (after MFMAs)
            __syncthreads();     // vmcnt(0)+lgkmcnt(0)+barrier: all staged
        }
    }

    const int lr = (lane >> 4) * 4;
    const int lc = lane & 15;
#pragma unroll
    for (int mi = 0; mi < 8; ++mi) {
#pragma unroll
        for (int r = 0; r < 4; ++r) {
            int gm = tile_m + wr + mi * 16 + lr + r;
            int bimg = gm / 576, pp2 = gm % 576;
            size_t orow = (size_t)bimg * SEQ + 1 + LSEQ + pp2;
#pragma unroll
            for (int ni = 0; ni < 4; ++ni) {
                int gn = tile_n + wc + ni * 16 + lc;
                float v = acc[mi][ni][r] + conv_b[gn] +
                          vis_pos[(size_t)(pp2 + 1) * 768 + gn] + mod[768 + gn];
                out[orow * 768 + gn] = v;
            }
        }
    }
}

// ---- CLS rows + masks ----
__global__ __launch_bounds__(256) void cls_masks(const float* __restrict__ cls,
                                                 const int* __restrict__ am,
                                                 float* __restrict__ out) {
    int t = blockIdx.x * 256 + threadIdx.x;
    if (t < NB * 768) {
        int b = t / 768, d = t % 768;
        out[(size_t)b * SEQ * 768 + d] = cls[d];
    } else if (t < NB * 768 + NB * SEQ) {
        int i = t - NB * 768;
        int b = i / SEQ, s = i % SEQ;
        float v = 1.0f;
        if (s >= 1 && s <= LSEQ) v = (float)am[b * LSEQ + s - 1];
        out[(size_t)NB * SEQ * 768 + i] = v;
    }
}

extern "C" void kernel_launch(void* const* d_in, const int* in_sizes, int n_in,
                              void* d_out, int out_size, void* d_ws, size_t ws_size,
                              hipStream_t stream) {
    const int*   ids  = (const int*)d_in[0];
    const int*   am   = (const int*)d_in[1];
    const int*   tti  = (const int*)d_in[2];
    const float* px   = (const float*)d_in[3];
    const float* we   = (const float*)d_in[5];
    const float* pe   = (const float*)d_in[6];
    const float* tke  = (const float*)d_in[7];
    const float* lng  = (const float*)d_in[8];
    const float* lnb  = (const float*)d_in[9];
    const float* cw   = (const float*)d_in[10];
    const float* cb   = (const float*)d_in[11];
    const float* cls  = (const float*)d_in[12];
    const float* vpos = (const float*)d_in[13];
    const float* mod  = (const float*)d_in[14];
    float* out = (float*)d_out;

    __bf16* Wbf = (__bf16*)d_ws;

    hipFuncSetAttribute((const void*)gemm_patch,
                        hipFuncAttributeMaxDynamicSharedMemorySize, GEMM_LDS);

    convert_w<<<288, 256, 0, stream>>>(cw, (unsigned short*)Wbf);
    text_kernel<<<640, 256, 0, stream>>>(ids, tti, we, pe, tke, lng, lnb, mod, out);
    gemm_patch<<<432, 512, GEMM_LDS, stream>>>(px, Wbf, cb, vpos, mod, out);
    cls_masks<<<347, 256, 0, stream>>>(cls, am, out);
}